// Round 6
// baseline (607.963 us; speedup 1.0000x reference)
//
#include <hip/hip_runtime.h>
#include <hip/hip_bf16.h>

// GraphSAGE 2-layer forward — edge-parallel LDS-atomic aggregation + MFMA.
//   zl = x@W1l, zr = x@W1r      (bf16 MFMA, SPLIT packed arrays [n,64])
//   h  = sigmoid(mean(zl) + zr + b1)            (h bf16 [n,64])
//   out = [mean(h) | h] @ [W2l;W2r] + b2        (fused gather+cat-GEMM)
//
// R6 changes vs 216µs:
//  - Aggregation restructured: flat edge-parallel accumulation into an LDS
//    fp32 tile via ds_add_f32 (atomicAdd on __shared__). Kills the shfl_xor
//    reduce storm (384 ds_bpermute/thread, serial 3-level tree) and all lane
//    waste; degree counted in a 65th acc column by the same atomics.
//  - dst-sortedness no longer needed -> bucket_build DELETED. Buckets are
//    64 nodes = one agg tile; ebuf is the tile edge list ((loc<<26)|src);
//    sbase gives tile edge ranges. csr/off gone.
//  - agg_h now ~20KB LDS -> ~7 blocks/CU (was 2.3) for latency hiding.
//  - 5 dispatches: prep_hist, scan, scatter+gemm1, agg_h, agg_gemm2.

#define N_FEAT 128
#define HID 64
#define NCLS 40
#define NE_BLK 2048
#define ECAP 768

typedef short short8 __attribute__((ext_vector_type(8)));
typedef float floatx4 __attribute__((ext_vector_type(4)));

static __device__ __forceinline__ short f2bf(float x) {
    __hip_bfloat16 h = __float2bfloat16(x);
    return __builtin_bit_cast(short, h);
}
static __device__ __forceinline__ float bf2f(unsigned short u) {
    unsigned int v = ((unsigned int)u) << 16;
    return __builtin_bit_cast(float, v);
}

// ---------------------------------------------------------------------------
// Weight prep (wt1 [128][128], wt2cat [48][128]) + 64-node-bucket histogram
// (LDS bins, key = dst>>6) + scan-flag zero. One dispatch, 293 blocks.
// ---------------------------------------------------------------------------
__global__ void prep_hist(const float* __restrict__ W1l, const float* __restrict__ W1r,
                          const float* __restrict__ W2l, const float* __restrict__ W2r,
                          unsigned short* __restrict__ wt1,
                          unsigned short* __restrict__ wt2,
                          int* __restrict__ flags,
                          const int* __restrict__ ei, int ne, int n,
                          int* __restrict__ bh, int nbe) {
    __shared__ int bins[2048];
    const int b = blockIdx.x, t = threadIdx.x;
    const int nbuck = (n + 63) >> 6;
    for (int i = t; i < nbuck; i += 256) bins[i] = 0;
    __syncthreads();
    const int e0 = b * NE_BLK;
    const int lim = (e0 + NE_BLK < ne) ? (e0 + NE_BLK) : ne;
    for (int e = e0 + t; e < lim; e += 256)
        atomicAdd(&bins[ei[ne + e] >> 6], 1);

    int i = b * 256 + t;
    if (i < 128 * 128) {
        int nn = i >> 7, k = i & 127;
        float v = (nn < 64) ? W1l[k * 64 + nn] : W1r[k * 64 + (nn - 64)];
        wt1[nn * 128 + k] = (unsigned short)f2bf(v);
    } else if (i < 128 * 128 + 48 * 128) {
        int j = i - 128 * 128;
        int nn = j >> 7, k = j & 127;
        float v = 0.f;
        if (nn < 40)
            v = (k < 64) ? W2l[k * 40 + nn] : W2r[(k - 64) * 40 + nn];
        wt2[nn * 128 + k] = (unsigned short)f2bf(v);
    }
    if (i < 256) flags[i] = 0;

    __syncthreads();
    for (int j = t; j < nbuck; j += 256) bh[(size_t)j * nbe + b] = bins[j];
}

// ---------------------------------------------------------------------------
// Lookback exclusive scan: pre[0]=0, pre[i]=sum(in[0..i-1]); m up to ~500K.
// ---------------------------------------------------------------------------
__global__ void scan_fused(const int* __restrict__ in, int* __restrict__ pre,
                           int m, int* __restrict__ bsums,
                           int* __restrict__ flags) {
    __shared__ int lds[256];
    __shared__ int look[256];
    __shared__ int sprefix;
    const int b = blockIdx.x, t = threadIdx.x;
    const int base = b * 2048 + t * 8;
    int v[8], s = 0;
#pragma unroll
    for (int i = 0; i < 8; ++i) {
        int idx = base + i;
        v[i] = (idx < m) ? in[idx] : 0;
        s += v[i];
    }
    lds[t] = s;
    __syncthreads();
    for (int o = 1; o < 256; o <<= 1) {
        int y = (t >= o) ? lds[t - o] : 0;
        __syncthreads();
        lds[t] += y;
        __syncthreads();
    }
    if (t == 255) {
        __hip_atomic_store(&bsums[b], lds[255], __ATOMIC_RELEASE,
                           __HIP_MEMORY_SCOPE_AGENT);
        __hip_atomic_store(&flags[b], 1, __ATOMIC_RELEASE,
                           __HIP_MEMORY_SCOPE_AGENT);
    }
    look[t] = 0;
    __syncthreads();
    if (t < b) {
        while (__hip_atomic_load(&flags[t], __ATOMIC_ACQUIRE,
                                 __HIP_MEMORY_SCOPE_AGENT) == 0) {}
        look[t] = __hip_atomic_load(&bsums[t], __ATOMIC_RELAXED,
                                    __HIP_MEMORY_SCOPE_AGENT);
    }
    __syncthreads();
    if (t == 0) {
        int p = 0;
        for (int i = 0; i < b; ++i) p += look[i];
        sprefix = p;
    }
    __syncthreads();
    int run = ((t == 0) ? 0 : lds[t - 1]) + sprefix;
#pragma unroll
    for (int i = 0; i < 8; ++i) {
        run += v[i];
        int idx = base + i;
        if (idx < m) pre[idx + 1] = run;
    }
    if (b == 0 && t == 0) pre[0] = 0;
}

// ---------------------------------------------------------------------------
// Layer-1 GEMM body (smem-pointer form for the heterogeneous kernel).
// ---------------------------------------------------------------------------
static __device__ __forceinline__ void gemm1_body(
    short* __restrict__ smem, const float* __restrict__ x,
    const unsigned short* __restrict__ Wt, unsigned short* __restrict__ Zl,
    unsigned short* __restrict__ Zr, int n, int bid) {
    constexpr int K = 128, LDA = K + 8, M = 128, MT = 8, KS = 4, QROW = 16;
    short* At = smem;             // 64 x LDA
    short* Bt = smem + 64 * LDA;  // 128 x LDA
    const int t = threadIdx.x;
    const int nodeBase = bid * 64;

    for (int q = t; q < 64 * QROW; q += 256) {
        int row = q / QROW;
        int k0 = (q % QROW) * 8;
        int node = nodeBase + row;
        short8 s = {0, 0, 0, 0, 0, 0, 0, 0};
        if (node < n) {
            const float* A = x + (size_t)node * K + k0;
            float4 v0 = *(const float4*)A;
            float4 v1 = *(const float4*)(A + 4);
            s[0] = f2bf(v0.x); s[1] = f2bf(v0.y);
            s[2] = f2bf(v0.z); s[3] = f2bf(v0.w);
            s[4] = f2bf(v1.x); s[5] = f2bf(v1.y);
            s[6] = f2bf(v1.z); s[7] = f2bf(v1.w);
        }
        *(short8*)&At[row * LDA + k0] = s;
    }
    for (int q = t; q < M * QROW; q += 256) {
        int row = q / QROW;
        int k0 = (q % QROW) * 8;
        *(short8*)&Bt[row * LDA + k0] =
            *(const short8*)((const short*)Wt + (size_t)row * K + k0);
    }
    __syncthreads();

    const int wave = t >> 6;
    const int lane = t & 63;
    const int m0 = wave * 16;
    const int fl = lane & 15;
    const int quad = lane >> 4;

    floatx4 acc[MT];
#pragma unroll
    for (int nt = 0; nt < MT; ++nt) acc[nt] = (floatx4){0.f, 0.f, 0.f, 0.f};

#pragma unroll
    for (int ks = 0; ks < KS; ++ks) {
        const int kb = ks * 32 + quad * 8;
        short8 a = *(const short8*)&At[(m0 + fl) * LDA + kb];
#pragma unroll
        for (int nt = 0; nt < MT; ++nt) {
            short8 b = *(const short8*)&Bt[(nt * 16 + fl) * LDA + kb];
            acc[nt] = __builtin_amdgcn_mfma_f32_16x16x32_bf16(a, b, acc[nt], 0, 0, 0);
        }
    }

#pragma unroll
    for (int nt = 0; nt < MT; ++nt) {
        const int col = nt * 16 + fl;
#pragma unroll
        for (int r = 0; r < 4; ++r) {
            int node = nodeBase + m0 + quad * 4 + r;
            if (node < n) {
                unsigned short v = (unsigned short)f2bf(acc[nt][r]);
                if (col < HID)
                    Zl[(size_t)node * HID + col] = v;
                else
                    Zr[(size_t)node * HID + (col - HID)] = v;
            }
        }
    }
}

// Heterogeneous launch: blocks [0,nbe) = bucket scatter (64-node buckets,
// packed (loc<<26)|src), rest = layer-1 GEMM tiles.
__global__ __launch_bounds__(256) void scatter_gemm1(
    const int* __restrict__ ei, int ne, int n, const int* __restrict__ sbase,
    unsigned* __restrict__ ebuf, int nbe, const float* __restrict__ x,
    const unsigned short* __restrict__ wt1, unsigned short* __restrict__ zl,
    unsigned short* __restrict__ zr) {
    __shared__ __align__(16) short smem[(64 + 128) * 136];
    const int b = blockIdx.x;
    if (b < nbe) {
        int* bins = (int*)smem;
        const int t = threadIdx.x;
        const int nbuck = (n + 63) >> 6;
        for (int i = t; i < nbuck; i += 256) bins[i] = 0;
        __syncthreads();
        const int e0 = b * NE_BLK;
        const int lim = (e0 + NE_BLK < ne) ? (e0 + NE_BLK) : ne;
        for (int e = e0 + t; e < lim; e += 256) {
            int d = ei[ne + e];
            int s = ei[e];
            int bk = d >> 6;
            int r = atomicAdd(&bins[bk], 1);
            int p = sbase[(size_t)bk * nbe + b] + r;
            ebuf[p] = ((unsigned)(d & 63) << 26) | (unsigned)s;
        }
    } else {
        gemm1_body(smem, x, wt1, zl, zr, n, b - nbe);
    }
}

// ---------------------------------------------------------------------------
// Edge-parallel gather body: accumulate neighbor rows of Z into the LDS
// fp32 tile acc[64][68] (col 64 = degree count) via ds_add_f32.
// Lane = (edge-slot g 0..7, chunk c 0..7); wave w takes edge range
// [nedge*w/4, nedge*(w+1)/4); slot g walks its 1/8 sub-segment.
// ---------------------------------------------------------------------------
static __device__ __forceinline__ void gather_acc(
    float* __restrict__ acc, const unsigned* __restrict__ elist,
    const unsigned* __restrict__ ebufE0, bool direct,
    const unsigned short* __restrict__ Z, int nedge) {
    const int t = threadIdx.x;
    const int w = t >> 6, lane = t & 63;
    const int g = lane >> 3, c = lane & 7;
    const int wl = (nedge * w) >> 2;
    const int wr = (nedge * (w + 1)) >> 2;
    const int wn = wr - wl;
    const int seg = (wn + 7) >> 3;
    const int sbeg = wl + g * seg;
#pragma unroll 2
    for (int r = 0; r < seg; ++r) {
        int e = sbeg + r;
        if (e < wr) {
            unsigned u = direct ? ebufE0[e] : elist[e];
            int loc = (int)(u >> 26);
            int src = (int)(u & 0x03FFFFFFu);
            uint4 v = *(const uint4*)(Z + (size_t)src * 64 + c * 8);
            float* a = acc + loc * 68 + c * 8;
            atomicAdd(a + 0, bf2f((unsigned short)(v.x & 0xffffu)));
            atomicAdd(a + 1, bf2f((unsigned short)(v.x >> 16)));
            atomicAdd(a + 2, bf2f((unsigned short)(v.y & 0xffffu)));
            atomicAdd(a + 3, bf2f((unsigned short)(v.y >> 16)));
            atomicAdd(a + 4, bf2f((unsigned short)(v.z & 0xffffu)));
            atomicAdd(a + 5, bf2f((unsigned short)(v.z >> 16)));
            atomicAdd(a + 6, bf2f((unsigned short)(v.w & 0xffffu)));
            atomicAdd(a + 7, bf2f((unsigned short)(v.w >> 16)));
            if (c == 0) atomicAdd(acc + loc * 68 + 64, 1.0f);
        }
    }
}

// ---------------------------------------------------------------------------
// Layer-1 aggregate: h = sigmoid(mean(Zl) + Zr + bias), bf16 out. ~20KB LDS.
// ---------------------------------------------------------------------------
__global__ __launch_bounds__(256) void agg_h(
    const unsigned short* __restrict__ Zl, const unsigned short* __restrict__ Zr,
    const unsigned* __restrict__ ebuf, const int* __restrict__ sbase, int nbe,
    const float* __restrict__ bias, unsigned short* __restrict__ hout, int n) {
    __shared__ float acc[64 * 68];
    __shared__ unsigned elist[ECAP];
    const int t = threadIdx.x;
    const int tile = blockIdx.x;
    const int base = tile * 64;
    const int E0 = sbase[(size_t)tile * nbe];
    const int E1 = sbase[(size_t)(tile + 1) * nbe];
    const int nedge = E1 - E0;
    for (int i = t; i < 64 * 68; i += 256) acc[i] = 0.f;
    const bool direct = (nedge > ECAP);
    if (!direct)
        for (int j = t; j < nedge; j += 256) elist[j] = ebuf[E0 + j];
    __syncthreads();

    gather_acc(acc, elist, ebuf + E0, direct, Zl, nedge);
    __syncthreads();

    for (int q = t; q < 512; q += 256) {
        int i = q >> 3, cc = q & 7;
        int node = base + i;
        if (node >= n) continue;
        float inv = 1.0f / fmaxf(acc[i * 68 + 64], 1.0f);
        const float* a = &acc[i * 68 + cc * 8];
        uint4 z = *(const uint4*)(Zr + (size_t)node * 64 + cc * 8);
        float4 b0 = ((const float4*)bias)[cc * 2];
        float4 b1 = ((const float4*)bias)[cc * 2 + 1];
        float rr[8];
        rr[0] = a[0] * inv + bf2f((unsigned short)(z.x & 0xffffu)) + b0.x;
        rr[1] = a[1] * inv + bf2f((unsigned short)(z.x >> 16)) + b0.y;
        rr[2] = a[2] * inv + bf2f((unsigned short)(z.y & 0xffffu)) + b0.z;
        rr[3] = a[3] * inv + bf2f((unsigned short)(z.y >> 16)) + b0.w;
        rr[4] = a[4] * inv + bf2f((unsigned short)(z.z & 0xffffu)) + b1.x;
        rr[5] = a[5] * inv + bf2f((unsigned short)(z.z >> 16)) + b1.y;
        rr[6] = a[6] * inv + bf2f((unsigned short)(z.w & 0xffffu)) + b1.z;
        rr[7] = a[7] * inv + bf2f((unsigned short)(z.w >> 16)) + b1.w;
#pragma unroll
        for (int j = 0; j < 8; ++j) rr[j] = 1.0f / (1.0f + __expf(-rr[j]));
        uint4 pk;
        pk.x = (unsigned int)(unsigned short)f2bf(rr[0]) |
               ((unsigned int)(unsigned short)f2bf(rr[1]) << 16);
        pk.y = (unsigned int)(unsigned short)f2bf(rr[2]) |
               ((unsigned int)(unsigned short)f2bf(rr[3]) << 16);
        pk.z = (unsigned int)(unsigned short)f2bf(rr[4]) |
               ((unsigned int)(unsigned short)f2bf(rr[5]) << 16);
        pk.w = (unsigned int)(unsigned short)f2bf(rr[6]) |
               ((unsigned int)(unsigned short)f2bf(rr[7]) << 16);
        *(uint4*)(hout + (size_t)node * 64 + cc * 8) = pk;
    }
}

// ---------------------------------------------------------------------------
// Fused layer-2: edge-parallel mean(h) -> acc -> bf16 A-tile left half;
// h staged right half; K=128 cat-GEMM; out = A@B + b2 (fp32 [n,40]).
// ---------------------------------------------------------------------------
__global__ __launch_bounds__(256) void agg_gemm2(
    const unsigned short* __restrict__ h, const unsigned short* __restrict__ Wt,
    const float* __restrict__ bias, const unsigned* __restrict__ ebuf,
    const int* __restrict__ sbase, int nbe, float* __restrict__ out, int n) {
    constexpr int LDA = 136;
    __shared__ __align__(16) short At[64 * LDA];
    __shared__ __align__(16) short Bt[48 * LDA];
    __shared__ float acc[64 * 68];
    __shared__ unsigned elist[ECAP];
    const int t = threadIdx.x;
    const int tile = blockIdx.x;
    const int base = tile * 64;
    const int E0 = sbase[(size_t)tile * nbe];
    const int E1 = sbase[(size_t)(tile + 1) * nbe];
    const int nedge = E1 - E0;
    for (int i = t; i < 64 * 68; i += 256) acc[i] = 0.f;
    const bool direct = (nedge > ECAP);
    if (!direct)
        for (int j = t; j < nedge; j += 256) elist[j] = ebuf[E0 + j];
    // stage h rows into At[:, 64:128)
    for (int q = t; q < 64 * 8; q += 256) {
        int row = q >> 3, k0 = (q & 7) * 8;
        int node = base + row;
        short8 s = {0, 0, 0, 0, 0, 0, 0, 0};
        if (node < n) s = *(const short8*)(h + (size_t)node * 64 + k0);
        *(short8*)&At[row * LDA + 64 + k0] = s;
    }
    // stage Bt (48 x 128)
    for (int q = t; q < 48 * 16; q += 256) {
        int row = q >> 4, k0 = (q & 15) * 8;
        *(short8*)&Bt[row * LDA + k0] =
            *(const short8*)((const short*)Wt + (size_t)row * 128 + k0);
    }
    __syncthreads();

    gather_acc(acc, elist, ebuf + E0, direct, h, nedge);
    __syncthreads();

    // acc -> At left half (bf16 mean)
    for (int q = t; q < 512; q += 256) {
        int i = q >> 3, cc = q & 7;
        float inv = 1.0f / fmaxf(acc[i * 68 + 64], 1.0f);
        const float* a = &acc[i * 68 + cc * 8];
        short8 s;
#pragma unroll
        for (int j = 0; j < 8; ++j) s[j] = f2bf(a[j] * inv);
        *(short8*)&At[i * LDA + cc * 8] = s;
    }
    __syncthreads();

    const int wave = t >> 6;
    const int lane = t & 63;
    const int m0 = wave * 16;
    const int fl = lane & 15;
    const int quad = lane >> 4;
    floatx4 accr[3];
#pragma unroll
    for (int nt = 0; nt < 3; ++nt) accr[nt] = (floatx4){0.f, 0.f, 0.f, 0.f};
#pragma unroll
    for (int ks = 0; ks < 4; ++ks) {
        const int kb = ks * 32 + quad * 8;
        short8 a = *(const short8*)&At[(m0 + fl) * LDA + kb];
#pragma unroll
        for (int nt = 0; nt < 3; ++nt) {
            short8 b = *(const short8*)&Bt[(nt * 16 + fl) * LDA + kb];
            accr[nt] = __builtin_amdgcn_mfma_f32_16x16x32_bf16(a, b, accr[nt], 0, 0, 0);
        }
    }
#pragma unroll
    for (int nt = 0; nt < 3; ++nt) {
        const int col = nt * 16 + fl;
        if (col < NCLS) {
            float bv = bias[col];
#pragma unroll
            for (int r = 0; r < 4; ++r) {
                int node = base + m0 + quad * 4 + r;
                if (node < n)
                    out[(size_t)node * NCLS + col] = accr[nt][r] + bv;
            }
        }
    }
}

// ---------------------------------------------------------------------------
extern "C" void kernel_launch(void* const* d_in, const int* in_sizes, int n_in,
                              void* d_out, int out_size, void* d_ws,
                              size_t ws_size, hipStream_t stream) {
    const float* x = (const float*)d_in[0];
    const int* ei = (const int*)d_in[1];
    const float* W1l = (const float*)d_in[2];
    const float* b1 = (const float*)d_in[3];
    const float* W1r = (const float*)d_in[4];
    const float* W2l = (const float*)d_in[5];
    const float* b2 = (const float*)d_in[6];
    const float* W2r = (const float*)d_in[7];
    float* out = (float*)d_out;

    const int n = in_sizes[0] / N_FEAT;  // 100000
    const int ne = in_sizes[1] / 2;      // 600000

    const int nbe = (ne + NE_BLK - 1) / NE_BLK;   // 293 edge blocks
    const int nbuck = (n + 63) >> 6;              // 1563 tiles
    const int tot = nbuck * nbe;                  // count-matrix size (~458K)

    // ws layout
    unsigned short* zl1 = (unsigned short*)d_ws;
    unsigned short* zr1 = zl1 + (size_t)n * HID;
    unsigned short* h = zr1 + (size_t)n * HID;
    unsigned short* wt1 = h + (size_t)n * HID;
    unsigned short* wt2 = wt1 + 128 * 128;
    unsigned* ebuf = (unsigned*)(wt2 + 48 * 128);
    int* bh = (int*)(ebuf + ne);
    int* sbase = bh + tot;
    int* bsums = sbase + (tot + 1);
    int* flags = bsums + 256;

    const int gblocks = (n + 63) / 64;            // 1563
    const int nsb = (tot + 2047) / 2048;          // 224 scan blocks

    // 1) weight prep + 64-node-bucket histogram + flag zero
    prep_hist<<<nbe, 256, 0, stream>>>(W1l, W1r, W2l, W2r, wt1, wt2, flags,
                                       ei, ne, n, bh, nbe);
    // 2) count-matrix scan -> per-(bucket,block) bases
    scan_fused<<<nsb, 256, 0, stream>>>(bh, sbase, tot, bsums, flags);
    // 3) bucket scatter + layer-1 GEMM (independent, heterogeneous blocks)
    scatter_gemm1<<<nbe + gblocks, 256, 0, stream>>>(ei, ne, n, sbase, ebuf,
                                                     nbe, x, wt1, zl1, zr1);
    // 4) layer-1 aggregate -> h
    agg_h<<<gblocks, 256, 0, stream>>>(zl1, zr1, ebuf, sbase, nbe, b1, h, n);
    // 5) fused layer-2 gather + cat-GEMM -> out
    agg_gemm2<<<gblocks, 256, 0, stream>>>(h, wt2, b2, ebuf, sbase, nbe, out, n);
}

// Round 7
// 188.153 us; speedup vs baseline: 3.2312x; 3.2312x over previous
//
#include <hip/hip_runtime.h>
#include <hip/hip_bf16.h>

// GraphSAGE 2-layer forward — CSR-gather + bf16 MFMA GEMMs.
//   zl = x@W1l, zr = x@W1r      (bf16 MFMA, SPLIT packed arrays [n,64])
//   h  = sigmoid(mean(zl) + zr + b1)            (h bf16 [n,64])
//   out = [mean(h) | h] @ [W2l;W2r] + b2        (fused gather+cat-GEMM)
//
// R7 = R5 structure (verified 216µs) + gather restructure:
//  - R6's LDS-atomic scatter REVERTED (flat-atomic RMW wall: 38.4M generic
//    per-feature atomics, 237µs with all pipes idle).
//  - R5's shfl_xor reduce storm (96 cross-lane ops/node-pair, ~4.8M DS-pipe
//    ops) replaced by half-wave-per-node accumulation: lane = dword column
//    (32 lanes = one 128B row), 2 fp32 accs/lane, NO cross-lane reduce.
//    Edge loads unroll-4 pipelined; indices from LDS tile edge list with
//    macro-split global/LDS paths (no generic pointers).

#define N_FEAT 128
#define HID 64
#define NCLS 40
#define NE_BLK 2048
#define ECAP 1536

typedef short short8 __attribute__((ext_vector_type(8)));
typedef float floatx4 __attribute__((ext_vector_type(4)));

static __device__ __forceinline__ short f2bf(float x) {
    __hip_bfloat16 h = __float2bfloat16(x);
    return __builtin_bit_cast(short, h);
}
static __device__ __forceinline__ float bf2f(unsigned short u) {
    unsigned int v = ((unsigned int)u) << 16;
    return __builtin_bit_cast(float, v);
}

// accumulate up to 4 edges (clamped index trick) of a 2-feat column slice.
// SRC is either the LDS elist or csr+E0 (global) — macro keeps addrspace.
#define GATHER2(SRC, Zsrc)                                                   \
    for (int r = 0; r < d; r += 4) {                                         \
        int i1 = (r + 1 < d) ? r + 1 : d - 1;                                \
        int i2 = (r + 2 < d) ? r + 2 : d - 1;                                \
        int i3 = (r + 3 < d) ? r + 3 : d - 1;                                \
        int j0 = SRC[s + r], j1 = SRC[s + i1];                               \
        int j2 = SRC[s + i2], j3 = SRC[s + i3];                              \
        unsigned v0 = *(const unsigned*)(Zsrc + (size_t)j0 * 64 + col * 2);  \
        unsigned v1 = *(const unsigned*)(Zsrc + (size_t)j1 * 64 + col * 2);  \
        unsigned v2 = *(const unsigned*)(Zsrc + (size_t)j2 * 64 + col * 2);  \
        unsigned v3 = *(const unsigned*)(Zsrc + (size_t)j3 * 64 + col * 2);  \
        float w1 = (r + 1 < d) ? 1.f : 0.f;                                  \
        float w2 = (r + 2 < d) ? 1.f : 0.f;                                  \
        float w3 = (r + 3 < d) ? 1.f : 0.f;                                  \
        ax += bf2f((unsigned short)(v0 & 0xffffu));                          \
        ay += bf2f((unsigned short)(v0 >> 16));                              \
        ax = fmaf(w1, bf2f((unsigned short)(v1 & 0xffffu)), ax);             \
        ay = fmaf(w1, bf2f((unsigned short)(v1 >> 16)), ay);                 \
        ax = fmaf(w2, bf2f((unsigned short)(v2 & 0xffffu)), ax);             \
        ay = fmaf(w2, bf2f((unsigned short)(v2 >> 16)), ay);                 \
        ax = fmaf(w3, bf2f((unsigned short)(v3 & 0xffffu)), ax);             \
        ay = fmaf(w3, bf2f((unsigned short)(v3 >> 16)), ay);                 \
    }

// ---------------------------------------------------------------------------
// Weight prep (wt1 [128][128], wt2cat [48][128] = [W2l;W2r]^T padded) +
// bucket histogram (LDS bins, key = dst>>8) + scan-flag zero. One dispatch.
// ---------------------------------------------------------------------------
__global__ void prep_hist(const float* __restrict__ W1l, const float* __restrict__ W1r,
                          const float* __restrict__ W2l, const float* __restrict__ W2r,
                          unsigned short* __restrict__ wt1,
                          unsigned short* __restrict__ wt2,
                          int* __restrict__ flags,
                          const int* __restrict__ ei, int ne, int n,
                          int* __restrict__ bh, int nbe) {
    __shared__ int bins[512];
    const int b = blockIdx.x, t = threadIdx.x;
    const int nbuck = (n + 255) >> 8;
    for (int i = t; i < nbuck; i += 256) bins[i] = 0;
    __syncthreads();
    const int e0 = b * NE_BLK;
    const int lim = (e0 + NE_BLK < ne) ? (e0 + NE_BLK) : ne;
    for (int e = e0 + t; e < lim; e += 256)
        atomicAdd(&bins[ei[ne + e] >> 8], 1);

    int i = b * 256 + t;
    if (i < 128 * 128) {
        int nn = i >> 7, k = i & 127;
        float v = (nn < 64) ? W1l[k * 64 + nn] : W1r[k * 64 + (nn - 64)];
        wt1[nn * 128 + k] = (unsigned short)f2bf(v);
    } else if (i < 128 * 128 + 48 * 128) {
        int j = i - 128 * 128;
        int nn = j >> 7, k = j & 127;
        float v = 0.f;
        if (nn < 40)
            v = (k < 64) ? W2l[k * 40 + nn] : W2r[(k - 64) * 40 + nn];
        wt2[nn * 128 + k] = (unsigned short)f2bf(v);
    }
    if (i < 256) flags[i] = 0;

    __syncthreads();
    for (int j = t; j < nbuck; j += 256) bh[j * nbe + b] = bins[j];
}

// ---------------------------------------------------------------------------
// Lookback exclusive scan: pre[0]=0, pre[i]=sum(in[0..i-1]).
// ---------------------------------------------------------------------------
__global__ void scan_fused(const int* __restrict__ in, int* __restrict__ pre,
                           int m, int* __restrict__ bsums,
                           int* __restrict__ flags) {
    __shared__ int lds[256];
    __shared__ int look[128];
    __shared__ int sprefix;
    const int b = blockIdx.x, t = threadIdx.x;
    const int base = b * 2048 + t * 8;
    int v[8], s = 0;
#pragma unroll
    for (int i = 0; i < 8; ++i) {
        int idx = base + i;
        v[i] = (idx < m) ? in[idx] : 0;
        s += v[i];
    }
    lds[t] = s;
    __syncthreads();
    for (int o = 1; o < 256; o <<= 1) {
        int y = (t >= o) ? lds[t - o] : 0;
        __syncthreads();
        lds[t] += y;
        __syncthreads();
    }
    if (t == 255) {
        __hip_atomic_store(&bsums[b], lds[255], __ATOMIC_RELEASE,
                           __HIP_MEMORY_SCOPE_AGENT);
        __hip_atomic_store(&flags[b], 1, __ATOMIC_RELEASE,
                           __HIP_MEMORY_SCOPE_AGENT);
    }
    if (t < 128) look[t] = 0;
    __syncthreads();
    if (t < b) {
        while (__hip_atomic_load(&flags[t], __ATOMIC_ACQUIRE,
                                 __HIP_MEMORY_SCOPE_AGENT) == 0) {}
        look[t] = __hip_atomic_load(&bsums[t], __ATOMIC_RELAXED,
                                    __HIP_MEMORY_SCOPE_AGENT);
    }
    __syncthreads();
    if (t == 0) {
        int p = 0;
        for (int i = 0; i < b; ++i) p += look[i];
        sprefix = p;
    }
    __syncthreads();
    int run = ((t == 0) ? 0 : lds[t - 1]) + sprefix;
#pragma unroll
    for (int i = 0; i < 8; ++i) {
        run += v[i];
        int idx = base + i;
        if (idx < m) pre[idx + 1] = run;
    }
    if (b == 0 && t == 0) pre[0] = 0;
}

// ---------------------------------------------------------------------------
// Layer-1 GEMM body (smem-pointer form for the heterogeneous kernel).
// ---------------------------------------------------------------------------
static __device__ __forceinline__ void gemm1_body(
    short* __restrict__ smem, const float* __restrict__ x,
    const unsigned short* __restrict__ Wt, unsigned short* __restrict__ Zl,
    unsigned short* __restrict__ Zr, int n, int bid) {
    constexpr int K = 128, LDA = K + 8, M = 128, MT = 8, KS = 4, QROW = 16;
    short* At = smem;             // 64 x LDA
    short* Bt = smem + 64 * LDA;  // 128 x LDA
    const int t = threadIdx.x;
    const int nodeBase = bid * 64;

    for (int q = t; q < 64 * QROW; q += 256) {
        int row = q / QROW;
        int k0 = (q % QROW) * 8;
        int node = nodeBase + row;
        short8 s = {0, 0, 0, 0, 0, 0, 0, 0};
        if (node < n) {
            const float* A = x + (size_t)node * K + k0;
            float4 v0 = *(const float4*)A;
            float4 v1 = *(const float4*)(A + 4);
            s[0] = f2bf(v0.x); s[1] = f2bf(v0.y);
            s[2] = f2bf(v0.z); s[3] = f2bf(v0.w);
            s[4] = f2bf(v1.x); s[5] = f2bf(v1.y);
            s[6] = f2bf(v1.z); s[7] = f2bf(v1.w);
        }
        *(short8*)&At[row * LDA + k0] = s;
    }
    for (int q = t; q < M * QROW; q += 256) {
        int row = q / QROW;
        int k0 = (q % QROW) * 8;
        *(short8*)&Bt[row * LDA + k0] =
            *(const short8*)((const short*)Wt + (size_t)row * K + k0);
    }
    __syncthreads();

    const int wave = t >> 6;
    const int lane = t & 63;
    const int m0 = wave * 16;
    const int fl = lane & 15;
    const int quad = lane >> 4;

    floatx4 acc[MT];
#pragma unroll
    for (int nt = 0; nt < MT; ++nt) acc[nt] = (floatx4){0.f, 0.f, 0.f, 0.f};

#pragma unroll
    for (int ks = 0; ks < KS; ++ks) {
        const int kb = ks * 32 + quad * 8;
        short8 a = *(const short8*)&At[(m0 + fl) * LDA + kb];
#pragma unroll
        for (int nt = 0; nt < MT; ++nt) {
            short8 b = *(const short8*)&Bt[(nt * 16 + fl) * LDA + kb];
            acc[nt] = __builtin_amdgcn_mfma_f32_16x16x32_bf16(a, b, acc[nt], 0, 0, 0);
        }
    }

#pragma unroll
    for (int nt = 0; nt < MT; ++nt) {
        const int col = nt * 16 + fl;
#pragma unroll
        for (int r = 0; r < 4; ++r) {
            int node = nodeBase + m0 + quad * 4 + r;
            if (node < n) {
                unsigned short v = (unsigned short)f2bf(acc[nt][r]);
                if (col < HID)
                    Zl[(size_t)node * HID + col] = v;
                else
                    Zr[(size_t)node * HID + (col - HID)] = v;
            }
        }
    }
}

// Heterogeneous launch: blocks [0,nbe) = bucket scatter, rest = layer-1 GEMM.
__global__ __launch_bounds__(256) void scatter_gemm1(
    const int* __restrict__ ei, int ne, int n, const int* __restrict__ sbase,
    int* __restrict__ ebuf, int nbe, const float* __restrict__ x,
    const unsigned short* __restrict__ wt1, unsigned short* __restrict__ zl,
    unsigned short* __restrict__ zr) {
    __shared__ __align__(16) short smem[(64 + 128) * 136];
    const int b = blockIdx.x;
    if (b < nbe) {
        int* bins = (int*)smem;
        const int t = threadIdx.x;
        const int nbuck = (n + 255) >> 8;
        for (int i = t; i < nbuck; i += 256) bins[i] = 0;
        __syncthreads();
        const int e0 = b * NE_BLK;
        const int lim = (e0 + NE_BLK < ne) ? (e0 + NE_BLK) : ne;
        for (int e = e0 + t; e < lim; e += 256) {
            int d = ei[ne + e];
            int s = ei[e];
            int bk = d >> 8;
            int r = atomicAdd(&bins[bk], 1);
            int p = sbase[bk * nbe + b] + r;
            ebuf[p] = (int)(((unsigned)(d & 255) << 24) | (unsigned)s);
        }
    } else {
        gemm1_body(smem, x, wt1, zl, zr, n, b - nbe);
    }
}

// one block per bucket: LDS 256-bin sub-histogram + scan -> off[] (coalesced)
// and csr reordered within the bucket's contiguous range.
__global__ void bucket_build(const int* __restrict__ ebuf,
                             const int* __restrict__ sbase, int nbe, int n,
                             int ne, int* __restrict__ off,
                             int* __restrict__ csr) {
    __shared__ int cnt[256];
    __shared__ int sc[256];
    __shared__ int pos[256];
    const int b = blockIdx.x;
    const int t = threadIdx.x;
    const int nbuck = (n + 255) >> 8;
    const int s0 = sbase[b * nbe];
    const int s1 = (b + 1 < nbuck) ? sbase[(b + 1) * nbe] : ne;
    cnt[t] = 0;
    __syncthreads();
    for (int i = s0 + t; i < s1; i += 256)
        atomicAdd(&cnt[((unsigned)ebuf[i]) >> 24], 1);
    __syncthreads();
    int v = cnt[t];
    sc[t] = v;
    __syncthreads();
    for (int o = 1; o < 256; o <<= 1) {
        int y = (t >= o) ? sc[t - o] : 0;
        __syncthreads();
        sc[t] += y;
        __syncthreads();
    }
    int g = b * 256 + t;
    if (g < n) off[g + 1] = s0 + sc[t];
    if (b == 0 && t == 0) off[0] = 0;
    pos[t] = s0 + sc[t] - v;  // exclusive
    __syncthreads();
    for (int i = s0 + t; i < s1; i += 256) {
        unsigned w = (unsigned)ebuf[i];
        int p = atomicAdd(&pos[w >> 24], 1);
        csr[p] = (int)(w & 0xFFFFFFu);
    }
}

// ---------------------------------------------------------------------------
// Layer-1 aggregate, 64-node tile per block, csr range staged to LDS once.
// Half-wave per node, lane = dword column (32 lanes = one 128B row), 2 fp32
// accs/lane, no cross-lane reduce. h = sigmoid(mean(Zl)+Zr+bias), bf16 out.
// ---------------------------------------------------------------------------
__global__ __launch_bounds__(256) void agg_h(
    const unsigned short* __restrict__ Zl, const unsigned short* __restrict__ Zr,
    const int* __restrict__ off, const int* __restrict__ csr,
    const float* __restrict__ bias, unsigned short* __restrict__ hout, int n) {
    __shared__ int offs[65];
    __shared__ int elist[ECAP];
    const int t = threadIdx.x;
    const int base = blockIdx.x * 64;
    if (t < 65) {
        int idx = base + t;
        offs[t] = off[(idx <= n) ? idx : n];
    }
    __syncthreads();
    const int E0 = offs[0];
    const int nedge = offs[64] - E0;
    const bool direct = (nedge > ECAP);
    if (!direct)
        for (int j = t; j < nedge; j += 256) elist[j] = csr[E0 + j];
    __syncthreads();

    const int lane = t & 63;
    const int wave = t >> 6;
    const int half = lane >> 5;
    const int col = lane & 31;
    const int* csrd = csr + E0;

    for (int p = 0; p < 8; ++p) {
        const int i = wave * 16 + 2 * p + half;
        const int node = base + i;
        const int s = offs[i] - E0;
        const int d = offs[i + 1] - offs[i];
        float ax = 0.f, ay = 0.f;
        if (direct) {
            GATHER2(csrd, Zl)
        } else {
            GATHER2(elist, Zl)
        }
        if (node < n) {
            float inv = 1.0f / fmaxf((float)d, 1.0f);
            unsigned z = *(const unsigned*)(Zr + (size_t)node * 64 + col * 2);
            float2 bb = ((const float2*)bias)[col];
            float rx = ax * inv + bf2f((unsigned short)(z & 0xffffu)) + bb.x;
            float ry = ay * inv + bf2f((unsigned short)(z >> 16)) + bb.y;
            rx = 1.0f / (1.0f + __expf(-rx));
            ry = 1.0f / (1.0f + __expf(-ry));
            unsigned pk = (unsigned)(unsigned short)f2bf(rx) |
                          ((unsigned)(unsigned short)f2bf(ry) << 16);
            *(unsigned*)(hout + (size_t)node * 64 + col * 2) = pk;
        }
    }
}

// ---------------------------------------------------------------------------
// Fused layer-2: gather-mean(h) (same half-wave structure) written as bf16
// straight into the MFMA A-tile left half; h staged right half; K=128
// cat-GEMM with wt2cat [48][128]; out = A@B + b2 (fp32 [n,40]).
// ---------------------------------------------------------------------------
__global__ __launch_bounds__(256) void agg_gemm2(
    const unsigned short* __restrict__ h, const unsigned short* __restrict__ Wt,
    const float* __restrict__ bias, const int* __restrict__ off,
    const int* __restrict__ csr, float* __restrict__ out, int n) {
    constexpr int LDA = 136;
    __shared__ __align__(16) short At[64 * LDA];
    __shared__ __align__(16) short Bt[48 * LDA];
    __shared__ int offs[65];
    __shared__ int elist[ECAP];
    const int t = threadIdx.x;
    const int base = blockIdx.x * 64;
    if (t < 65) {
        int idx = base + t;
        offs[t] = off[(idx <= n) ? idx : n];
    }
    __syncthreads();
    const int E0 = offs[0];
    const int nedge = offs[64] - E0;
    const bool direct = (nedge > ECAP);
    if (!direct)
        for (int j = t; j < nedge; j += 256) elist[j] = csr[E0 + j];
    // stage h rows into At[:, 64:128)
    for (int q = t; q < 64 * 8; q += 256) {
        int row = q >> 3, k0 = (q & 7) * 8;
        int node = base + row;
        short8 s = {0, 0, 0, 0, 0, 0, 0, 0};
        if (node < n) s = *(const short8*)(h + (size_t)node * 64 + k0);
        *(short8*)&At[row * LDA + 64 + k0] = s;
    }
    // stage Bt (48 x 128)
    for (int q = t; q < 48 * 16; q += 256) {
        int row = q >> 4, k0 = (q & 15) * 8;
        *(short8*)&Bt[row * LDA + k0] =
            *(const short8*)((const short*)Wt + (size_t)row * 128 + k0);
    }
    __syncthreads();

    // gather phase: mean over neighbors of h -> At[:, 0:64)
    const int lane = t & 63;
    const int wave = t >> 6;
    const int half = lane >> 5;
    const int col = lane & 31;
    const int* csrd = csr + E0;
    for (int p = 0; p < 8; ++p) {
        const int i = wave * 16 + 2 * p + half;
        const int s = offs[i] - E0;
        const int d = offs[i + 1] - offs[i];
        float ax = 0.f, ay = 0.f;
        if (direct) {
            GATHER2(csrd, h)
        } else {
            GATHER2(elist, h)
        }
        float inv = 1.0f / fmaxf((float)d, 1.0f);
        unsigned pk = (unsigned)(unsigned short)f2bf(ax * inv) |
                      ((unsigned)(unsigned short)f2bf(ay * inv) << 16);
        *(unsigned*)&At[i * LDA + col * 2] = pk;  // zero rows for node>=n
    }
    __syncthreads();

    // MFMA: K=128, 3 col-tiles (48 cols, 40 valid)
    const int m0 = wave * 16;
    const int fl = lane & 15;
    const int quad = lane >> 4;
    floatx4 acc[3];
#pragma unroll
    for (int nt = 0; nt < 3; ++nt) acc[nt] = (floatx4){0.f, 0.f, 0.f, 0.f};
#pragma unroll
    for (int ks = 0; ks < 4; ++ks) {
        const int kb = ks * 32 + quad * 8;
        short8 a = *(const short8*)&At[(m0 + fl) * LDA + kb];
#pragma unroll
        for (int nt = 0; nt < 3; ++nt) {
            short8 b = *(const short8*)&Bt[(nt * 16 + fl) * LDA + kb];
            acc[nt] = __builtin_amdgcn_mfma_f32_16x16x32_bf16(a, b, acc[nt], 0, 0, 0);
        }
    }
#pragma unroll
    for (int nt = 0; nt < 3; ++nt) {
        const int col2 = nt * 16 + fl;
        if (col2 < NCLS) {
            float bv = bias[col2];
#pragma unroll
            for (int r = 0; r < 4; ++r) {
                int node = base + m0 + quad * 4 + r;
                if (node < n)
                    out[(size_t)node * NCLS + col2] = acc[nt][r] + bv;
            }
        }
    }
}

// ---------------------------------------------------------------------------
extern "C" void kernel_launch(void* const* d_in, const int* in_sizes, int n_in,
                              void* d_out, int out_size, void* d_ws,
                              size_t ws_size, hipStream_t stream) {
    const float* x = (const float*)d_in[0];
    const int* ei = (const int*)d_in[1];
    const float* W1l = (const float*)d_in[2];
    const float* b1 = (const float*)d_in[3];
    const float* W1r = (const float*)d_in[4];
    const float* W2l = (const float*)d_in[5];
    const float* b2 = (const float*)d_in[6];
    const float* W2r = (const float*)d_in[7];
    float* out = (float*)d_out;

    const int n = in_sizes[0] / N_FEAT;  // 100000
    const int ne = in_sizes[1] / 2;      // 600000

    const int nbe = (ne + NE_BLK - 1) / NE_BLK;   // 293 edge blocks
    const int nbuck = (n + 255) >> 8;             // 391 buckets
    const int tot = nbuck * nbe;                  // count-matrix size

    // ws layout
    unsigned short* zl1 = (unsigned short*)d_ws;
    unsigned short* zr1 = zl1 + (size_t)n * HID;
    unsigned short* h = zr1 + (size_t)n * HID;
    unsigned short* wt1 = h + (size_t)n * HID;
    unsigned short* wt2 = wt1 + 128 * 128;
    int* off = (int*)(wt2 + 48 * 128);
    int* csr = off + (n + 1);
    int* ebuf = csr + ne;
    int* bh = ebuf + ne;
    int* sbase = bh + tot;
    int* bsums = sbase + (tot + 1);
    int* flags = bsums + 256;

    const int gblocks = (n + 63) / 64;            // 1563
    const int nsb = (tot + 2047) / 2048;          // 56 scan blocks

    // 1) weight prep + bucket histogram + flag zero
    prep_hist<<<nbe, 256, 0, stream>>>(W1l, W1r, W2l, W2r, wt1, wt2, flags,
                                       ei, ne, n, bh, nbe);
    // 2) count-matrix scan
    scan_fused<<<nsb, 256, 0, stream>>>(bh, sbase, tot, bsums, flags);
    // 3) bucket scatter + layer-1 GEMM (independent, heterogeneous blocks)
    scatter_gemm1<<<nbe + gblocks, 256, 0, stream>>>(ei, ne, n, sbase, ebuf,
                                                     nbe, x, wt1, zl1, zr1);
    // 4) per-bucket CSR finalize
    bucket_build<<<nbuck, 256, 0, stream>>>(ebuf, sbase, nbe, n, ne, off, csr);
    // 5) layer-1 aggregate -> h
    agg_h<<<gblocks, 256, 0, stream>>>(zl1, zr1, off, csr, b1, h, n);
    // 6) fused layer-2 gather + cat-GEMM -> out
    agg_gemm2<<<gblocks, 256, 0, stream>>>(h, wt2, b2, off, csr, out, n);
}

// Round 8
// 186.350 us; speedup vs baseline: 3.2625x; 1.0097x over previous
//
#include <hip/hip_runtime.h>
#include <hip/hip_bf16.h>

// GraphSAGE 2-layer forward — CSR-gather + bf16 MFMA GEMMs.
//   zl = x@W1l, zr = x@W1r      (bf16 MFMA, SPLIT packed arrays [n,64])
//   h  = sigmoid(mean(zl) + zr + b1)            (h bf16 [n,64])
//   out = [mean(h) | h] @ [W2l;W2r] + b2        (fused gather+cat-GEMM)
//
// R8 changes vs 188µs:
//  - bucket_build DELETED: buckets are now 64 nodes (= one agg tile, packed
//    (loc6<<26)|src). Each agg block counting-sorts its own ~384 edges in
//    LDS (64-bin cnt + t0-prefix + scatter to elist), chunked for any size.
//    csr/off arrays gone; one less dispatch + ~10MB less global traffic.
//  - GATHER4 quarter-wave gather: lane = uint2 column (16 lanes = 128B row),
//    4 node-chains per wave -> half the gather load instrs of R7's GATHER2,
//    2x the independent memory chains. agg_h LDS ~4.6KB (high occupancy).
//  - 5 dispatches: prep_hist, scan, scatter+gemm1, agg_h, agg_gemm2.

#define N_FEAT 128
#define HID 64
#define NCLS 40
#define NE_BLK 4096
#define ECAP 1024

typedef short short8 __attribute__((ext_vector_type(8)));
typedef float floatx4 __attribute__((ext_vector_type(4)));

static __device__ __forceinline__ short f2bf(float x) {
    __hip_bfloat16 h = __float2bfloat16(x);
    return __builtin_bit_cast(short, h);
}
static __device__ __forceinline__ float bf2f(unsigned short u) {
    unsigned int v = ((unsigned int)u) << 16;
    return __builtin_bit_cast(float, v);
}

// accumulate up to 4 edges (clamped-index trick) of a 4-feat (uint2) column.
// SRC = LDS elist (sorted srcs). Uses s, d, col from scope; acc into AC[0..3].
#define GATHER4(SRC, Zsrc, AC)                                               \
    for (int r = 0; r < d; r += 4) {                                         \
        int i1 = (r + 1 < d) ? r + 1 : d - 1;                                \
        int i2 = (r + 2 < d) ? r + 2 : d - 1;                                \
        int i3 = (r + 3 < d) ? r + 3 : d - 1;                                \
        int j0 = SRC[s + r], j1 = SRC[s + i1];                               \
        int j2 = SRC[s + i2], j3 = SRC[s + i3];                              \
        uint2 v0 = *(const uint2*)(Zsrc + (size_t)j0 * 64 + col * 4);        \
        uint2 v1 = *(const uint2*)(Zsrc + (size_t)j1 * 64 + col * 4);        \
        uint2 v2 = *(const uint2*)(Zsrc + (size_t)j2 * 64 + col * 4);        \
        uint2 v3 = *(const uint2*)(Zsrc + (size_t)j3 * 64 + col * 4);        \
        float w1 = (r + 1 < d) ? 1.f : 0.f;                                  \
        float w2 = (r + 2 < d) ? 1.f : 0.f;                                  \
        float w3 = (r + 3 < d) ? 1.f : 0.f;                                  \
        AC[0] += bf2f((unsigned short)(v0.x & 0xffffu));                     \
        AC[1] += bf2f((unsigned short)(v0.x >> 16));                         \
        AC[2] += bf2f((unsigned short)(v0.y & 0xffffu));                     \
        AC[3] += bf2f((unsigned short)(v0.y >> 16));                         \
        AC[0] = fmaf(w1, bf2f((unsigned short)(v1.x & 0xffffu)), AC[0]);     \
        AC[1] = fmaf(w1, bf2f((unsigned short)(v1.x >> 16)), AC[1]);         \
        AC[2] = fmaf(w1, bf2f((unsigned short)(v1.y & 0xffffu)), AC[2]);     \
        AC[3] = fmaf(w1, bf2f((unsigned short)(v1.y >> 16)), AC[3]);         \
        AC[0] = fmaf(w2, bf2f((unsigned short)(v2.x & 0xffffu)), AC[0]);     \
        AC[1] = fmaf(w2, bf2f((unsigned short)(v2.x >> 16)), AC[1]);         \
        AC[2] = fmaf(w2, bf2f((unsigned short)(v2.y & 0xffffu)), AC[2]);     \
        AC[3] = fmaf(w2, bf2f((unsigned short)(v2.y >> 16)), AC[3]);         \
        AC[0] = fmaf(w3, bf2f((unsigned short)(v3.x & 0xffffu)), AC[0]);     \
        AC[1] = fmaf(w3, bf2f((unsigned short)(v3.x >> 16)), AC[1]);         \
        AC[2] = fmaf(w3, bf2f((unsigned short)(v3.y & 0xffffu)), AC[2]);     \
        AC[3] = fmaf(w3, bf2f((unsigned short)(v3.y >> 16)), AC[3]);         \
    }

// per-chunk in-LDS counting sort of [E0+c0, E0+c0+cn) into elist (sorted by
// local dst). Reads ebuf twice (L2-hot). Leaves cnt[i]=deg_i, pos[i]=end_i.
#define TILE_SORT()                                                          \
    __syncthreads(); /* protect elist/cnt from previous chunk's gather */    \
    if (t < 64) cnt[t] = 0;                                                  \
    __syncthreads();                                                         \
    for (int j = t; j < cn; j += 256)                                        \
        atomicAdd(&cnt[ebuf[E0 + c0 + j] >> 26], 1);                         \
    __syncthreads();                                                         \
    if (t == 0) {                                                            \
        int run = 0;                                                         \
        for (int i = 0; i < 64; ++i) { pos[i] = run; run += cnt[i]; }        \
    }                                                                        \
    __syncthreads();                                                         \
    for (int j = t; j < cn; j += 256) {                                      \
        unsigned u = ebuf[E0 + c0 + j];                                      \
        int r = atomicAdd(&pos[u >> 26], 1);                                 \
        elist[r] = (int)(u & 0x03FFFFFFu);                                   \
    }                                                                        \
    __syncthreads();

// ---------------------------------------------------------------------------
// Weight prep (wt1 [128][128], wt2cat [48][128]) + 64-node-bucket histogram
// (LDS bins, key = dst>>6) + scan-flag zero. One dispatch, 147 blocks.
// ---------------------------------------------------------------------------
__global__ void prep_hist(const float* __restrict__ W1l, const float* __restrict__ W1r,
                          const float* __restrict__ W2l, const float* __restrict__ W2r,
                          unsigned short* __restrict__ wt1,
                          unsigned short* __restrict__ wt2,
                          int* __restrict__ flags,
                          const int* __restrict__ ei, int ne, int n,
                          int* __restrict__ bh, int nbe) {
    __shared__ int bins[2048];
    const int b = blockIdx.x, t = threadIdx.x;
    const int nbuck = (n + 63) >> 6;
    for (int i = t; i < nbuck; i += 256) bins[i] = 0;
    __syncthreads();
    const int e0 = b * NE_BLK;
    const int lim = (e0 + NE_BLK < ne) ? (e0 + NE_BLK) : ne;
    for (int e = e0 + t; e < lim; e += 256)
        atomicAdd(&bins[ei[ne + e] >> 6], 1);

    int i = b * 256 + t;
    if (i < 128 * 128) {
        int nn = i >> 7, k = i & 127;
        float v = (nn < 64) ? W1l[k * 64 + nn] : W1r[k * 64 + (nn - 64)];
        wt1[nn * 128 + k] = (unsigned short)f2bf(v);
    } else if (i < 128 * 128 + 48 * 128) {
        int j = i - 128 * 128;
        int nn = j >> 7, k = j & 127;
        float v = 0.f;
        if (nn < 40)
            v = (k < 64) ? W2l[k * 40 + nn] : W2r[(k - 64) * 40 + nn];
        wt2[nn * 128 + k] = (unsigned short)f2bf(v);
    }
    if (i < 256) flags[i] = 0;

    __syncthreads();
    for (int j = t; j < nbuck; j += 256) bh[(size_t)j * nbe + b] = bins[j];
}

// ---------------------------------------------------------------------------
// Lookback exclusive scan: pre[0]=0, pre[i]=sum(in[0..i-1]); m ~230K.
// ---------------------------------------------------------------------------
__global__ void scan_fused(const int* __restrict__ in, int* __restrict__ pre,
                           int m, int* __restrict__ bsums,
                           int* __restrict__ flags) {
    __shared__ int lds[256];
    __shared__ int look[128];
    __shared__ int sprefix;
    const int b = blockIdx.x, t = threadIdx.x;
    const int base = b * 2048 + t * 8;
    int v[8], s = 0;
#pragma unroll
    for (int i = 0; i < 8; ++i) {
        int idx = base + i;
        v[i] = (idx < m) ? in[idx] : 0;
        s += v[i];
    }
    lds[t] = s;
    __syncthreads();
    for (int o = 1; o < 256; o <<= 1) {
        int y = (t >= o) ? lds[t - o] : 0;
        __syncthreads();
        lds[t] += y;
        __syncthreads();
    }
    if (t == 255) {
        __hip_atomic_store(&bsums[b], lds[255], __ATOMIC_RELEASE,
                           __HIP_MEMORY_SCOPE_AGENT);
        __hip_atomic_store(&flags[b], 1, __ATOMIC_RELEASE,
                           __HIP_MEMORY_SCOPE_AGENT);
    }
    if (t < 128) look[t] = 0;
    __syncthreads();
    if (t < b) {
        while (__hip_atomic_load(&flags[t], __ATOMIC_ACQUIRE,
                                 __HIP_MEMORY_SCOPE_AGENT) == 0) {}
        look[t] = __hip_atomic_load(&bsums[t], __ATOMIC_RELAXED,
                                    __HIP_MEMORY_SCOPE_AGENT);
    }
    __syncthreads();
    if (t == 0) {
        int p = 0;
        for (int i = 0; i < b; ++i) p += look[i];
        sprefix = p;
    }
    __syncthreads();
    int run = ((t == 0) ? 0 : lds[t - 1]) + sprefix;
#pragma unroll
    for (int i = 0; i < 8; ++i) {
        run += v[i];
        int idx = base + i;
        if (idx < m) pre[idx + 1] = run;
    }
    if (b == 0 && t == 0) pre[0] = 0;
}

// ---------------------------------------------------------------------------
// Layer-1 GEMM body (smem-pointer form for the heterogeneous kernel).
// ---------------------------------------------------------------------------
static __device__ __forceinline__ void gemm1_body(
    short* __restrict__ smem, const float* __restrict__ x,
    const unsigned short* __restrict__ Wt, unsigned short* __restrict__ Zl,
    unsigned short* __restrict__ Zr, int n, int bid) {
    constexpr int K = 128, LDA = K + 8, M = 128, MT = 8, KS = 4, QROW = 16;
    short* At = smem;             // 64 x LDA
    short* Bt = smem + 64 * LDA;  // 128 x LDA
    const int t = threadIdx.x;
    const int nodeBase = bid * 64;

    for (int q = t; q < 64 * QROW; q += 256) {
        int row = q / QROW;
        int k0 = (q % QROW) * 8;
        int node = nodeBase + row;
        short8 s = {0, 0, 0, 0, 0, 0, 0, 0};
        if (node < n) {
            const float* A = x + (size_t)node * K + k0;
            float4 v0 = *(const float4*)A;
            float4 v1 = *(const float4*)(A + 4);
            s[0] = f2bf(v0.x); s[1] = f2bf(v0.y);
            s[2] = f2bf(v0.z); s[3] = f2bf(v0.w);
            s[4] = f2bf(v1.x); s[5] = f2bf(v1.y);
            s[6] = f2bf(v1.z); s[7] = f2bf(v1.w);
        }
        *(short8*)&At[row * LDA + k0] = s;
    }
    for (int q = t; q < M * QROW; q += 256) {
        int row = q / QROW;
        int k0 = (q % QROW) * 8;
        *(short8*)&Bt[row * LDA + k0] =
            *(const short8*)((const short*)Wt + (size_t)row * K + k0);
    }
    __syncthreads();

    const int wave = t >> 6;
    const int lane = t & 63;
    const int m0 = wave * 16;
    const int fl = lane & 15;
    const int quad = lane >> 4;

    floatx4 acc[MT];
#pragma unroll
    for (int nt = 0; nt < MT; ++nt) acc[nt] = (floatx4){0.f, 0.f, 0.f, 0.f};

#pragma unroll
    for (int ks = 0; ks < KS; ++ks) {
        const int kb = ks * 32 + quad * 8;
        short8 a = *(const short8*)&At[(m0 + fl) * LDA + kb];
#pragma unroll
        for (int nt = 0; nt < MT; ++nt) {
            short8 b = *(const short8*)&Bt[(nt * 16 + fl) * LDA + kb];
            acc[nt] = __builtin_amdgcn_mfma_f32_16x16x32_bf16(a, b, acc[nt], 0, 0, 0);
        }
    }

#pragma unroll
    for (int nt = 0; nt < MT; ++nt) {
        const int col = nt * 16 + fl;
#pragma unroll
        for (int r = 0; r < 4; ++r) {
            int node = nodeBase + m0 + quad * 4 + r;
            if (node < n) {
                unsigned short v = (unsigned short)f2bf(acc[nt][r]);
                if (col < HID)
                    Zl[(size_t)node * HID + col] = v;
                else
                    Zr[(size_t)node * HID + (col - HID)] = v;
            }
        }
    }
}

// Heterogeneous launch: blocks [0,nbe) = bucket scatter (64-node buckets,
// packed (loc<<26)|src), rest = layer-1 GEMM tiles.
__global__ __launch_bounds__(256) void scatter_gemm1(
    const int* __restrict__ ei, int ne, int n, const int* __restrict__ sbase,
    unsigned* __restrict__ ebuf, int nbe, const float* __restrict__ x,
    const unsigned short* __restrict__ wt1, unsigned short* __restrict__ zl,
    unsigned short* __restrict__ zr) {
    __shared__ __align__(16) short smem[(64 + 128) * 136];
    const int b = blockIdx.x;
    if (b < nbe) {
        int* bins = (int*)smem;
        const int t = threadIdx.x;
        const int nbuck = (n + 63) >> 6;
        for (int i = t; i < nbuck; i += 256) bins[i] = 0;
        __syncthreads();
        const int e0 = b * NE_BLK;
        const int lim = (e0 + NE_BLK < ne) ? (e0 + NE_BLK) : ne;
        for (int e = e0 + t; e < lim; e += 256) {
            int d = ei[ne + e];
            int s = ei[e];
            int bk = d >> 6;
            int r = atomicAdd(&bins[bk], 1);
            int p = sbase[(size_t)bk * nbe + b] + r;
            ebuf[p] = ((unsigned)(d & 63) << 26) | (unsigned)s;
        }
    } else {
        gemm1_body(smem, x, wt1, zl, zr, n, b - nbe);
    }
}

// ---------------------------------------------------------------------------
// Layer-1 aggregate, 64-node tile per block. In-LDS counting sort of the
// tile's edges, then quarter-wave gather (lane = uint2 column, 4 node-chains
// per wave). h = sigmoid(mean(Zl)+Zr+bias), bf16 out. ~4.6KB LDS.
// ---------------------------------------------------------------------------
__global__ __launch_bounds__(256) void agg_h(
    const unsigned short* __restrict__ Zl, const unsigned short* __restrict__ Zr,
    const unsigned* __restrict__ ebuf, const int* __restrict__ sbase, int nbe,
    const float* __restrict__ bias, unsigned short* __restrict__ hout, int n) {
    __shared__ int elist[ECAP];
    __shared__ int cnt[64];
    __shared__ int pos[64];
    const int t = threadIdx.x;
    const int tile = blockIdx.x;
    const int base = tile * 64;
    const int E0 = sbase[(size_t)tile * nbe];
    const int E1 = sbase[(size_t)(tile + 1) * nbe];
    const int nedge = E1 - E0;

    const int lane = t & 63, wave = t >> 6;
    const int sub = lane >> 4, col = lane & 15;

    float a[4][4];
    int totd[4];
#pragma unroll
    for (int p = 0; p < 4; ++p) {
        totd[p] = 0;
#pragma unroll
        for (int j = 0; j < 4; ++j) a[p][j] = 0.f;
    }

    for (int c0 = 0; c0 < nedge; c0 += ECAP) {
        const int cn = (nedge - c0 < ECAP) ? (nedge - c0) : ECAP;
        TILE_SORT()
#pragma unroll
        for (int p = 0; p < 4; ++p) {
            const int i = wave * 16 + p * 4 + sub;
            const int s = pos[i] - cnt[i];
            const int d = cnt[i];
            totd[p] += d;
            float* AC = a[p];
            GATHER4(elist, Zl, AC)
        }
    }

#pragma unroll
    for (int p = 0; p < 4; ++p) {
        const int i = wave * 16 + p * 4 + sub;
        const int node = base + i;
        if (node < n) {
            float inv = 1.0f / fmaxf((float)totd[p], 1.0f);
            uint2 z = *(const uint2*)(Zr + (size_t)node * 64 + col * 4);
            float4 bb = ((const float4*)bias)[col];
            float r0 = a[p][0] * inv + bf2f((unsigned short)(z.x & 0xffffu)) + bb.x;
            float r1 = a[p][1] * inv + bf2f((unsigned short)(z.x >> 16)) + bb.y;
            float r2 = a[p][2] * inv + bf2f((unsigned short)(z.y & 0xffffu)) + bb.z;
            float r3 = a[p][3] * inv + bf2f((unsigned short)(z.y >> 16)) + bb.w;
            r0 = 1.0f / (1.0f + __expf(-r0));
            r1 = 1.0f / (1.0f + __expf(-r1));
            r2 = 1.0f / (1.0f + __expf(-r2));
            r3 = 1.0f / (1.0f + __expf(-r3));
            uint2 pk;
            pk.x = (unsigned)(unsigned short)f2bf(r0) |
                   ((unsigned)(unsigned short)f2bf(r1) << 16);
            pk.y = (unsigned)(unsigned short)f2bf(r2) |
                   ((unsigned)(unsigned short)f2bf(r3) << 16);
            *(uint2*)(hout + (size_t)node * 64 + col * 4) = pk;
        }
    }
}

// ---------------------------------------------------------------------------
// Fused layer-2: in-LDS sort + quarter-wave gather-mean(h) -> bf16 A-tile
// left half; h staged right half; K=128 cat-GEMM; out = A@B + b2 (fp32).
// ---------------------------------------------------------------------------
__global__ __launch_bounds__(256) void agg_gemm2(
    const unsigned short* __restrict__ h, const unsigned short* __restrict__ Wt,
    const float* __restrict__ bias, const unsigned* __restrict__ ebuf,
    const int* __restrict__ sbase, int nbe, float* __restrict__ out, int n) {
    constexpr int LDA = 136;
    __shared__ __align__(16) short At[64 * LDA];
    __shared__ __align__(16) short Bt[48 * LDA];
    __shared__ int elist[ECAP];
    __shared__ int cnt[64];
    __shared__ int pos[64];
    const int t = threadIdx.x;
    const int tile = blockIdx.x;
    const int base = tile * 64;
    const int E0 = sbase[(size_t)tile * nbe];
    const int E1 = sbase[(size_t)(tile + 1) * nbe];
    const int nedge = E1 - E0;

    // stage h rows into At[:, 64:128)
    for (int q = t; q < 64 * 8; q += 256) {
        int row = q >> 3, k0 = (q & 7) * 8;
        int node = base + row;
        short8 s = {0, 0, 0, 0, 0, 0, 0, 0};
        if (node < n) s = *(const short8*)(h + (size_t)node * 64 + k0);
        *(short8*)&At[row * LDA + 64 + k0] = s;
    }
    // stage Bt (48 x 128)
    for (int q = t; q < 48 * 16; q += 256) {
        int row = q >> 4, k0 = (q & 15) * 8;
        *(short8*)&Bt[row * LDA + k0] =
            *(const short8*)((const short*)Wt + (size_t)row * 128 + k0);
    }

    const int lane = t & 63, wave = t >> 6;
    const int sub = lane >> 4, col = lane & 15;

    float a[4][4];
    int totd[4];
#pragma unroll
    for (int p = 0; p < 4; ++p) {
        totd[p] = 0;
#pragma unroll
        for (int j = 0; j < 4; ++j) a[p][j] = 0.f;
    }

    for (int c0 = 0; c0 < nedge; c0 += ECAP) {
        const int cn = (nedge - c0 < ECAP) ? (nedge - c0) : ECAP;
        TILE_SORT()
#pragma unroll
        for (int p = 0; p < 4; ++p) {
            const int i = wave * 16 + p * 4 + sub;
            const int s = pos[i] - cnt[i];
            const int d = cnt[i];
            totd[p] += d;
            float* AC = a[p];
            GATHER4(elist, h, AC)
        }
    }

    // gather epilogue -> At left half (bf16 mean; zero rows for node>=n)
#pragma unroll
    for (int p = 0; p < 4; ++p) {
        const int i = wave * 16 + p * 4 + sub;
        float inv = 1.0f / fmaxf((float)totd[p], 1.0f);
        uint2 pk;
        pk.x = (unsigned)(unsigned short)f2bf(a[p][0] * inv) |
               ((unsigned)(unsigned short)f2bf(a[p][1] * inv) << 16);
        pk.y = (unsigned)(unsigned short)f2bf(a[p][2] * inv) |
               ((unsigned)(unsigned short)f2bf(a[p][3] * inv) << 16);
        *(uint2*)&At[i * LDA + col * 4] = pk;
    }
    __syncthreads();

    // MFMA: K=128, 3 col-tiles (48 cols, 40 valid)
    const int m0 = wave * 16;
    const int fl = lane & 15;
    const int quad = lane >> 4;
    floatx4 acc[3];
#pragma unroll
    for (int nt = 0; nt < 3; ++nt) acc[nt] = (floatx4){0.f, 0.f, 0.f, 0.f};
#pragma unroll
    for (int ks = 0; ks < 4; ++ks) {
        const int kb = ks * 32 + quad * 8;
        short8 av = *(const short8*)&At[(m0 + fl) * LDA + kb];
#pragma unroll
        for (int nt = 0; nt < 3; ++nt) {
            short8 bv = *(const short8*)&Bt[(nt * 16 + fl) * LDA + kb];
            acc[nt] = __builtin_amdgcn_mfma_f32_16x16x32_bf16(av, bv, acc[nt], 0, 0, 0);
        }
    }
#pragma unroll
    for (int nt = 0; nt < 3; ++nt) {
        const int col2 = nt * 16 + fl;
        if (col2 < NCLS) {
            float bv = bias[col2];
#pragma unroll
            for (int r = 0; r < 4; ++r) {
                int node = base + m0 + quad * 4 + r;
                if (node < n)
                    out[(size_t)node * NCLS + col2] = acc[nt][r] + bv;
            }
        }
    }
}

// ---------------------------------------------------------------------------
extern "C" void kernel_launch(void* const* d_in, const int* in_sizes, int n_in,
                              void* d_out, int out_size, void* d_ws,
                              size_t ws_size, hipStream_t stream) {
    const float* x = (const float*)d_in[0];
    const int* ei = (const int*)d_in[1];
    const float* W1l = (const float*)d_in[2];
    const float* b1 = (const float*)d_in[3];
    const float* W1r = (const float*)d_in[4];
    const float* W2l = (const float*)d_in[5];
    const float* b2 = (const float*)d_in[6];
    const float* W2r = (const float*)d_in[7];
    float* out = (float*)d_out;

    const int n = in_sizes[0] / N_FEAT;  // 100000
    const int ne = in_sizes[1] / 2;      // 600000

    const int nbe = (ne + NE_BLK - 1) / NE_BLK;   // 147 edge blocks
    const int nbuck = (n + 63) >> 6;              // 1563 tiles
    const int tot = nbuck * nbe;                  // ~230K

    // ws layout
    unsigned short* zl1 = (unsigned short*)d_ws;
    unsigned short* zr1 = zl1 + (size_t)n * HID;
    unsigned short* h = zr1 + (size_t)n * HID;
    unsigned short* wt1 = h + (size_t)n * HID;
    unsigned short* wt2 = wt1 + 128 * 128;
    unsigned* ebuf = (unsigned*)(wt2 + 48 * 128);
    int* bh = (int*)(ebuf + ne);
    int* sbase = bh + tot;
    int* bsums = sbase + (tot + 1);
    int* flags = bsums + 256;

    const int gblocks = (n + 63) / 64;            // 1563
    const int nsb = (tot + 2047) / 2048;          // 113 scan blocks

    // 1) weight prep + 64-node-bucket histogram + flag zero
    prep_hist<<<nbe, 256, 0, stream>>>(W1l, W1r, W2l, W2r, wt1, wt2, flags,
                                       ei, ne, n, bh, nbe);
    // 2) count-matrix scan -> per-(bucket,block) bases
    scan_fused<<<nsb, 256, 0, stream>>>(bh, sbase, tot, bsums, flags);
    // 3) bucket scatter + layer-1 GEMM (independent, heterogeneous blocks)
    scatter_gemm1<<<nbe + gblocks, 256, 0, stream>>>(ei, ne, n, sbase, ebuf,
                                                     nbe, x, wt1, zl1, zr1);
    // 4) layer-1 aggregate -> h
    agg_h<<<gblocks, 256, 0, stream>>>(zl1, zr1, ebuf, sbase, nbe, b1, h, n);
    // 5) fused layer-2 sort+gather + cat-GEMM -> out
    agg_gemm2<<<gblocks, 256, 0, stream>>>(h, wt2, b2, ebuf, sbase, nbe, out, n);
}